// Round 8
// baseline (171.212 us; speedup 1.0000x reference)
//
#include <hip/hip_runtime.h>
#include <hip/hip_bf16.h>

// SimpleOrdinalLinearDecayEmbedding: out[m,d] = gate[m] * (q[m,:]@Wq[d,:]) + bq[d]
// gate[m] = sigmoid(sum_k max(1-|k-r[m]|/3,0)*Wr[k] + br), r in {0..3} -> LUT.
// M = 32768, K = 800, N = 64.
//
// R5/R6/R7 all plateaued at ~48-56us. Invariant found: aggregate VMEM bytes /
// time ~= 6.3-6.8 TB/s across all structures (R4 512MB/75us, R7 307MB/49us) =
// ~10 B/cyc/CU, the measured per-CU vector-load service rate. The binder is
// per-CU VMEM byte throughput, NOT latency -> pipelining tweaks were neutral.
// B-fragment traffic dominated (205 MB: every 16-row wave privately re-read the
// 100 KB blob).
//
// R8: 64 rows per wave (4 row-tiles x 4 col-tiles = 16 accumulators) amortizes
// B 4x: traffic 307 -> 165 MB (A 105 + B 51 + out 8). K-split kept (khalf 0:
// kt 0..12, khalf 1: kt 13..24; fp32 partials combined in 16 KB LDS, validated
// in R5) -> 512 blocks x 128 thr, 4 waves/CU. DEPTH=3 register pipeline with
// sched_barrier(0) pinning (~36 KB in flight/wave). ~240 VGPR (no-spill range).

#define QD 800
#define DD 64
#define M_TOTAL 32768
#define KT 25      // 800 / 32
#define KSPLIT 13  // khalf0: kt 0..12 (13), khalf1: kt 13..24 (12)
#define DEPTH 3

typedef __attribute__((ext_vector_type(8))) short bf16x8;
typedef __attribute__((ext_vector_type(4))) float f32x4;

static __device__ __forceinline__ short f2bf(float f) {
  union { __hip_bfloat16 h; short s; } u;
  u.h = __float2bfloat16(f);
  return u.s;
}

static __device__ __forceinline__ bf16x8 pack8(f32x4 lo, f32x4 hi) {
  bf16x8 r;
  r[0] = f2bf(lo.x); r[1] = f2bf(lo.y); r[2] = f2bf(lo.z); r[3] = f2bf(lo.w);
  r[4] = f2bf(hi.x); r[5] = f2bf(hi.y); r[6] = f2bf(hi.z); r[7] = f2bf(hi.w);
  return r;
}

// sigma(lhi,j) = (j<4 ? lhi*4+j : 16+lhi*4+j-4): lo ksegs at +0, hi at +16 floats.
static __device__ __forceinline__ bf16x8 load_split8(const float* __restrict__ p) {
  return pack8(*reinterpret_cast<const f32x4*>(p),
               *reinterpret_cast<const f32x4*>(p + 16));
}

// Prep: B blob. Chunk idx = (kt*4 + c)*64 + lane holds the 8 bf16 B-fragment
// values for (kt, c, lane): Wq[c*16+(lane&15)][kt*32+sigma]. 100 KB, L2-hot.
__global__ void convert_wq_kernel(const float* __restrict__ Wq, short* __restrict__ Bb) {
  int idx = blockIdx.x * 256 + threadIdx.x;  // 6400 threads
  int kt = idx >> 8;
  int c = (idx >> 6) & 3;
  int lane = idx & 63;
  int l15 = lane & 15, lhi = lane >> 4;
  const float* p = Wq + (c * 16 + l15) * QD + kt * 32 + lhi * 4;
  *reinterpret_cast<bf16x8*>(Bb + (size_t)idx * 8) = load_split8(p);
}

// DEPTH-stage register pipeline over CNT k-tiles; 4 row-tiles share 4 B frags.
template <int CNT>
static __device__ __forceinline__ void pipe_loop(
    const float* __restrict__ a0, const float* __restrict__ a1,
    const float* __restrict__ a2, const float* __restrict__ a3,
    const short* __restrict__ bp, f32x4 (&acc)[4][4]) {
  const float* at[4] = {a0, a1, a2, a3};
  f32x4 sAlo[DEPTH][4], sAhi[DEPTH][4];
  bf16x8 sB[DEPTH][4];

#pragma unroll
  for (int s = 0; s < DEPTH; ++s) {
    if (s < CNT) {
#pragma unroll
      for (int t = 0; t < 4; ++t) {
        sAlo[s][t] = *reinterpret_cast<const f32x4*>(at[t] + s * 32);
        sAhi[s][t] = *reinterpret_cast<const f32x4*>(at[t] + s * 32 + 16);
      }
#pragma unroll
      for (int c = 0; c < 4; ++c)
        sB[s][c] = *reinterpret_cast<const bf16x8*>(bp + s * 2048 + c * 512);
    }
  }

#pragma unroll
  for (int kt = 0; kt < CNT; ++kt) {
    const int s = kt % DEPTH;
    bf16x8 afr[4];
#pragma unroll
    for (int t = 0; t < 4; ++t) afr[t] = pack8(sAlo[s][t], sAhi[s][t]);
#pragma unroll
    for (int t = 0; t < 4; ++t)
#pragma unroll
      for (int c = 0; c < 4; ++c)
        acc[t][c] = __builtin_amdgcn_mfma_f32_16x16x32_bf16(afr[t], sB[s][c],
                                                            acc[t][c], 0, 0, 0);
    const int nx = kt + DEPTH;
    if (nx < CNT) {
#pragma unroll
      for (int t = 0; t < 4; ++t) {
        sAlo[s][t] = *reinterpret_cast<const f32x4*>(at[t] + nx * 32);
        sAhi[s][t] = *reinterpret_cast<const f32x4*>(at[t] + nx * 32 + 16);
      }
#pragma unroll
      for (int c = 0; c < 4; ++c)
        sB[s][c] = *reinterpret_cast<const bf16x8*>(bp + nx * 2048 + c * 512);
    }
    __builtin_amdgcn_sched_barrier(0);  // pin the modulo schedule
  }
}

// 512 blocks x 128 thr: wave = khalf; both waves cover rows m0..m0+63.
__global__ __launch_bounds__(128, 1) void sold_kernel(
    const float* __restrict__ q, const int* __restrict__ rdat,
    const short* __restrict__ Bb, const float* __restrict__ bq,
    const float* __restrict__ Wr, const float* __restrict__ br,
    float* __restrict__ out) {
  const int lane = threadIdx.x & 63;
  const int khalf = threadIdx.x >> 6;
  const int l15 = lane & 15;
  const int lhi = lane >> 4;
  const int m0 = blockIdx.x * 64;
  const int kt0 = khalf ? KSPLIT : 0;

  const float* a0 = q + (size_t)(m0 +  0 + l15) * QD + kt0 * 32 + lhi * 4;
  const float* a1 = q + (size_t)(m0 + 16 + l15) * QD + kt0 * 32 + lhi * 4;
  const float* a2 = q + (size_t)(m0 + 32 + l15) * QD + kt0 * 32 + lhi * 4;
  const float* a3 = q + (size_t)(m0 + 48 + l15) * QD + kt0 * 32 + lhi * 4;
  const short* bp = Bb + (size_t)kt0 * 2048 + lane * 8;

  f32x4 acc[4][4];
#pragma unroll
  for (int t = 0; t < 4; ++t)
#pragma unroll
    for (int c = 0; c < 4; ++c) acc[t][c] = {0.f, 0.f, 0.f, 0.f};

  if (khalf == 0) {
    pipe_loop<KSPLIT>(a0, a1, a2, a3, bp, acc);
  } else {
    pipe_loop<KT - KSPLIT>(a0, a1, a2, a3, bp, acc);
  }

  // K-split combine (R5-validated): khalf1 publishes, khalf0 reduces + epilogue.
  __shared__ float comb[4][16][64];  // 16 KB; [tile][c*4+r][lane], lane-contiguous
  if (khalf == 1) {
#pragma unroll
    for (int t = 0; t < 4; ++t)
#pragma unroll
      for (int c = 0; c < 4; ++c)
#pragma unroll
        for (int r = 0; r < 4; ++r) comb[t][c * 4 + r][lane] = acc[t][c][r];
  }
  __syncthreads();
  if (khalf == 1) return;

#pragma unroll
  for (int t = 0; t < 4; ++t)
#pragma unroll
    for (int c = 0; c < 4; ++c)
#pragma unroll
      for (int r = 0; r < 4; ++r) acc[t][c][r] += comb[t][c * 4 + r][lane];

  // Gate LUT: r in {0..3}; weights w[k] = max(1-|k-r|/3, 0).
  float wr[4] = {Wr[0], Wr[1], Wr[2], Wr[3]};
  float brv = br[0];
  float lut[4];
  const float inv3 = 1.0f / 3.0f;
#pragma unroll
  for (int r = 0; r < 4; ++r) {
    float s = brv;
#pragma unroll
    for (int k = 0; k < 4; ++k)
      s += fmaxf(1.0f - fabsf((float)(k - r)) * inv3, 0.0f) * wr[k];
    lut[r] = 1.0f / (1.0f + __expf(-s));
  }

  float bqv[4];
#pragma unroll
  for (int c = 0; c < 4; ++c) bqv[c] = bq[c * 16 + l15];

  // D layout (HW-verified m89): col = lane&15 (+16 per c), row = (lane>>4)*4 + r.
#pragma unroll
  for (int t = 0; t < 4; ++t) {
#pragma unroll
    for (int r = 0; r < 4; ++r) {
      int row = m0 + t * 16 + lhi * 4 + r;
      float g = lut[rdat[row]];
      float* orow = out + (size_t)row * DD + l15;
#pragma unroll
      for (int c = 0; c < 4; ++c) orow[c * 16] = acc[t][c][r] * g + bqv[c];
    }
  }
}

// Fallback (ws too small — not expected): R4-style direct from fp32 Wq.
__global__ __launch_bounds__(256, 2) void sold_direct(
    const float* __restrict__ q, const int* __restrict__ rdat,
    const float* __restrict__ Wq, const float* __restrict__ bq,
    const float* __restrict__ Wr, const float* __restrict__ br,
    float* __restrict__ out) {
  const int lane = threadIdx.x & 63;
  const int wave = threadIdx.x >> 6;
  const int l15 = lane & 15;
  const int lhi = lane >> 4;
  const int m0 = blockIdx.x * 64 + wave * 16;
  const float* aptr = q + (size_t)(m0 + l15) * QD + lhi * 4;
  const float* w0 = Wq + (0 * 16 + l15) * QD + lhi * 4;
  const float* w1 = Wq + (1 * 16 + l15) * QD + lhi * 4;
  const float* w2 = Wq + (2 * 16 + l15) * QD + lhi * 4;
  const float* w3 = Wq + (3 * 16 + l15) * QD + lhi * 4;
  f32x4 acc0 = {0.f,0.f,0.f,0.f}, acc1 = {0.f,0.f,0.f,0.f};
  f32x4 acc2 = {0.f,0.f,0.f,0.f}, acc3 = {0.f,0.f,0.f,0.f};
#pragma unroll 5
  for (int kt = 0; kt < KT; ++kt) {
    bf16x8 a  = load_split8(aptr + kt * 32);
    bf16x8 b0 = load_split8(w0 + kt * 32);
    bf16x8 b1 = load_split8(w1 + kt * 32);
    bf16x8 b2 = load_split8(w2 + kt * 32);
    bf16x8 b3 = load_split8(w3 + kt * 32);
    acc0 = __builtin_amdgcn_mfma_f32_16x16x32_bf16(a, b0, acc0, 0, 0, 0);
    acc1 = __builtin_amdgcn_mfma_f32_16x16x32_bf16(a, b1, acc1, 0, 0, 0);
    acc2 = __builtin_amdgcn_mfma_f32_16x16x32_bf16(a, b2, acc2, 0, 0, 0);
    acc3 = __builtin_amdgcn_mfma_f32_16x16x32_bf16(a, b3, acc3, 0, 0, 0);
  }
  float wr[4] = {Wr[0], Wr[1], Wr[2], Wr[3]};
  float brv = br[0], lut[4];
  const float inv3 = 1.0f / 3.0f;
#pragma unroll
  for (int r = 0; r < 4; ++r) {
    float s = brv;
#pragma unroll
    for (int k = 0; k < 4; ++k)
      s += fmaxf(1.0f - fabsf((float)(k - r)) * inv3, 0.0f) * wr[k];
    lut[r] = 1.0f / (1.0f + __expf(-s));
  }
  float bqv0 = bq[l15], bqv1 = bq[16 + l15], bqv2 = bq[32 + l15], bqv3 = bq[48 + l15];
#pragma unroll
  for (int r = 0; r < 4; ++r) {
    int row = m0 + lhi * 4 + r;
    float g = lut[rdat[row]];
    float* orow = out + (size_t)row * DD + l15;
    orow[0]  = acc0[r] * g + bqv0;
    orow[16] = acc1[r] * g + bqv1;
    orow[32] = acc2[r] * g + bqv2;
    orow[48] = acc3[r] * g + bqv3;
  }
}

extern "C" void kernel_launch(void* const* d_in, const int* in_sizes, int n_in,
                              void* d_out, int out_size, void* d_ws, size_t ws_size,
                              hipStream_t stream) {
  const float* q    = (const float*)d_in[0];  // [64,512,800] f32
  const int*   rdat = (const int*)d_in[1];    // [64,512] i32
  const float* Wq   = (const float*)d_in[2];  // [64,800] f32
  const float* bq   = (const float*)d_in[3];  // [64] f32
  const float* Wr   = (const float*)d_in[4];  // [1,4] f32
  const float* br   = (const float*)d_in[5];  // [1] f32
  float* out = (float*)d_out;                 // [64,512,64] f32

  const size_t need_ws = (size_t)KT * 2048 * sizeof(short);  // 102400 B
  if (ws_size >= need_ws) {
    short* Bb = (short*)d_ws;
    convert_wq_kernel<<<KT, 256, 0, stream>>>(Wq, Bb);
    sold_kernel<<<M_TOTAL / 64, 128, 0, stream>>>(q, rdat, Bb, bq, Wr, br, out);
  } else {
    sold_direct<<<M_TOTAL / 64, 256, 0, stream>>>(q, rdat, Wq, bq, Wr, br, out);
  }
}